// Round 9
// baseline (3050.469 us; speedup 1.0000x reference)
//
#include <hip/hip_runtime.h>
#include <math.h>

#define NB 64      // batch
#define NP 12      // encoder steps
#define NQ 12      // decoder steps
#define NT 24      // P+Q
#define NN 325     // nodes
#define ND 64      // units
#define NR 20800   // NN*NB rows
#define CAP 64     // max nnz per S row (mean ~20.5)
#define TSZ 1331200  // NR*ND
#define CH 2304    // LDS chunk size in u16 (32 rows x stride 72)

typedef __attribute__((ext_vector_type(8))) short frag8;
typedef __attribute__((ext_vector_type(4))) float f32x4;
typedef unsigned short u16;

__device__ inline u16 f2bf(float f) {
  unsigned u = __builtin_bit_cast(unsigned, f);
  unsigned r = u + 0x7FFFu + ((u >> 16) & 1u);
  return (u16)(r >> 16);
}
__device__ inline float bf2f(u16 h) {
  unsigned u = ((unsigned)h) << 16;
  return __builtin_bit_cast(float, u);
}
__device__ inline void split8v(const float* v, frag8& hi, frag8& lo) {
  #pragma unroll
  for (int i = 0; i < 8; i++) {
    u16 h = f2bf(v[i]);
    hi[i] = (short)h;
    lo[i] = (short)f2bf(v[i] - bf2f(h));
  }
}

__global__ void k_te(const int* __restrict__ TE, const float* __restrict__ W1,
                     const float* __restrict__ b1, const float* __restrict__ W2,
                     const float* __restrict__ b2, float* __restrict__ te) {
  int row = blockIdx.x;            // b*24+t
  int d = threadIdx.x;
  __shared__ float s[ND];
  int wd = TE[row * 2 + 0], td = TE[row * 2 + 1];
  float v = W1[wd * ND + d] + W1[(7 + td) * ND + d] + b1[d];
  s[d] = v > 0.f ? v : 0.f;
  __syncthreads();
  float acc = b2[d];
  #pragma unroll 8
  for (int k = 0; k < ND; k++) acc = fmaf(s[k], W2[k * ND + d], acc);
  te[row * ND + d] = acc;
}

__global__ void k_zero(float* __restrict__ p, int n) {
  int i = blockIdx.x * 256 + threadIdx.x;
  if (i < n) p[i] = 0.f;
}

// W (384 x nw) fp32 -> k-major bf16 hi/lo: Wh/Wl[n*384 + k]
__global__ void k_convW(const float* __restrict__ W, u16* __restrict__ Wh,
                        u16* __restrict__ Wl, int nw) {
  int k = blockIdx.x;
  int n = threadIdx.x;
  float w = W[k * nw + n];
  u16 h = f2bf(w);
  Wh[n * 384 + k] = h;
  Wl[n * 384 + k] = f2bf(w - bf2f(h));
}

// CSR build for S0/S1 + row sums
__global__ void k_csr(const float* __restrict__ S0g, const float* __restrict__ S1g,
                      int* __restrict__ cnt, int* __restrict__ idx,
                      float* __restrict__ val, float* __restrict__ rsum) {
  int m = blockIdx.x, z = blockIdx.y;
  const float* S = z ? S1g : S0g;
  int lane = threadIdx.x;
  int c = 0;
  float psum = 0.f;
  for (int k0 = 0; k0 < NN; k0 += 64) {
    int k = k0 + lane;
    float v = (k < NN) ? S[m * NN + k] : 0.f;
    psum += v;
    bool p = (v != 0.f);
    unsigned long long mask = __ballot(p);
    int pos = c + __popcll(mask & ((1ull << lane) - 1ull));
    if (p) {
      idx[(z * NN + m) * CAP + pos] = k;
      val[(z * NN + m) * CAP + pos] = v;
    }
    c += __popcll(mask);
  }
  #pragma unroll
  for (int off = 32; off > 0; off >>= 1) psum += __shfl_down(psum, off);
  if (lane == 0) { cnt[z * NN + m] = c; rsum[z * NN + m] = psum; }
}

// SE[z][m][d] = (S_z @ E_se)[m][d]
__global__ void k_se(const float* __restrict__ E, const int* __restrict__ cnt,
                     const int* __restrict__ idx, const float* __restrict__ val,
                     float* __restrict__ SE) {
  int m = blockIdx.x, z = blockIdx.y, d = threadIdx.x;
  int n = cnt[z * NN + m];
  float a = 0.f;
  for (int j = 0; j < n; j++)
    a = fmaf(val[(z * NN + m) * CAP + j], E[idx[(z * NN + m) * CAP + j] * ND + d], a);
  SE[(size_t)(z * NN + m) * ND + d] = a;
}

// Encoder-only Xe[t][row][d]. 16 rows/block, 4 d per thread.
__global__ void k_xe(const float* __restrict__ X, const float* __restrict__ te,
                     const float* __restrict__ E_se, const float* __restrict__ Wi1,
                     const float* __restrict__ bi1, const float* __restrict__ Wi2,
                     const float* __restrict__ bi2, float* __restrict__ Xe) {
  int t = blockIdx.y;
  int r = threadIdx.x >> 4;
  int row = blockIdx.x * 16 + r;
  int n = row >> 6, b = row & 63;
  int dq = (threadIdx.x & 15) * 4;
  float4 tev = *(const float4*)&te[(b * NT + t) * ND + dq];
  float4 ev  = *(const float4*)&E_se[n * ND + dq];
  __shared__ float s[16][65];
  float x = X[(b * NP + t) * NN + n];
  float4 w1 = *(const float4*)&Wi1[dq];
  float4 b1 = *(const float4*)&bi1[dq];
  s[r][dq + 0] = fmaxf(fmaf(x, w1.x, b1.x), 0.f);
  s[r][dq + 1] = fmaxf(fmaf(x, w1.y, b1.y), 0.f);
  s[r][dq + 2] = fmaxf(fmaf(x, w1.z, b1.z), 0.f);
  s[r][dq + 3] = fmaxf(fmaf(x, w1.w, b1.w), 0.f);
  __syncthreads();
  float4 acc = *(const float4*)&bi2[dq];
  #pragma unroll 8
  for (int k = 0; k < ND; k++) {
    float sv = s[r][k];
    float4 w2 = *(const float4*)&Wi2[k * ND + dq];
    acc.x = fmaf(sv, w2.x, acc.x); acc.y = fmaf(sv, w2.y, acc.y);
    acc.z = fmaf(sv, w2.z, acc.z); acc.w = fmaf(sv, w2.w, acc.w);
  }
  acc.x += tev.x + ev.x; acc.y += tev.y + ev.y;
  acc.z += tev.z + ev.z; acc.w += tev.w + ev.w;
  *(float4*)&Xe[(size_t)t * TSZ + (size_t)row * ND + dq] = acc;
}

// Pre-gather S@Xe for all encoder steps -> bf16 hi/lo planes.
__global__ void k_sxe(const float* __restrict__ Xe, const int* __restrict__ cnt,
                      const int* __restrict__ idx, const float* __restrict__ val,
                      u16* __restrict__ SXH, u16* __restrict__ SXL) {
  int xc = blockIdx.x, m = blockIdx.y, t = blockIdx.z;
  int tid = threadIdx.x;
  int z = tid >> 7, lid = tid & 127;
  int c = xc * 512 + lid * 4;
  __shared__ int sI[2][CAP];
  __shared__ float sV[2][CAP];
  __shared__ int scnt[2];
  if (tid < 2) scnt[tid] = cnt[tid * NN + m];
  __syncthreads();
  int n = scnt[z];
  if (lid < n) {
    sI[z][lid] = idx[(z * NN + m) * CAP + lid];
    sV[z][lid] = val[(z * NN + m) * CAP + lid];
  }
  __syncthreads();
  float4 aa = make_float4(0.f, 0.f, 0.f, 0.f);
  const float* base = Xe + (size_t)t * TSZ + c;
  for (int j = 0; j < n; j++) {
    float v = sV[z][j];
    float4 x = *(const float4*)(base + (size_t)sI[z][j] * 4096);
    aa.x = fmaf(v, x.x, aa.x); aa.y = fmaf(v, x.y, aa.y);
    aa.z = fmaf(v, x.z, aa.z); aa.w = fmaf(v, x.w, aa.w);
  }
  size_t o = (size_t)(t * 2 + z) * TSZ + (size_t)m * 4096 + c;
  u16 h0 = f2bf(aa.x), h1 = f2bf(aa.y), h2 = f2bf(aa.z), h3 = f2bf(aa.w);
  ushort4 hv = {h0, h1, h2, h3};
  ushort4 lv = {f2bf(aa.x - bf2f(h0)), f2bf(aa.y - bf2f(h1)),
                f2bf(aa.z - bf2f(h2)), f2bf(aa.w - bf2f(h3))};
  *(ushort4*)&SXH[o] = hv;
  *(ushort4*)&SXL[o] = lv;
}

// ---------- Fused gate kernel: inline S@h gather + K=384 MFMA + sigmoid ----------
// Block = (node m, batch-half g), 32-row panel. Chunks: 0=x 1=h 2=S0x 3=S0h 4=S1x 5=S1h.
// LDS chunk rows: stride 72 u16 (64 K + 8 pad).
template<int ENC>
__global__ void __launch_bounds__(256, 2)
k_FG(int t, const float* __restrict__ Xe, const u16* __restrict__ SXH,
     const u16* __restrict__ SXL, const float* __restrict__ te,
     const float* __restrict__ E_se, const float* __restrict__ SE,
     const float* __restrict__ rs, const float* __restrict__ h,
     const int* __restrict__ cnt, const int* __restrict__ idx,
     const float* __restrict__ val, const u16* __restrict__ Wh,
     const u16* __restrict__ Wl, const float* __restrict__ bias,
     float* __restrict__ rh, float* __restrict__ ubuf) {
  int m = blockIdx.x >> 1, g = blockIdx.x & 1;
  int tid = threadIdx.x;
  int lane = tid & 63, w = tid >> 6;
  __shared__ u16 Ah[6 * CH], Al[6 * CH];
  __shared__ u16 Bh[128 * 40], Bl[128 * 40];
  __shared__ int sI[2][CAP];
  __shared__ float sV[2][CAP];
  __shared__ int scnt[2];
  if (tid < 2) scnt[tid] = cnt[tid * NN + m];
  __syncthreads();

  int r = tid >> 3, kf = (tid & 7) * 8;
  int b = g * 32 + r;
  size_t own = (size_t)(m * 64 + b) * ND + kf;
  frag8 fh, fl;
  float v8[8];
  float4 t0, t1;
  if (ENC) {
    float4 a = *(const float4*)&Xe[(size_t)t * TSZ + own];
    float4 c4 = *(const float4*)&Xe[(size_t)t * TSZ + own + 4];
    v8[0] = a.x; v8[1] = a.y; v8[2] = a.z; v8[3] = a.w;
    v8[4] = c4.x; v8[5] = c4.y; v8[6] = c4.z; v8[7] = c4.w;
  } else {
    t0 = *(const float4*)&te[(size_t)(b * NT + t) * ND + kf];
    t1 = *(const float4*)&te[(size_t)(b * NT + t) * ND + kf + 4];
    float4 e0 = *(const float4*)&E_se[m * ND + kf];
    float4 e1 = *(const float4*)&E_se[m * ND + kf + 4];
    v8[0] = t0.x + e0.x; v8[1] = t0.y + e0.y; v8[2] = t0.z + e0.z; v8[3] = t0.w + e0.w;
    v8[4] = t1.x + e1.x; v8[5] = t1.y + e1.y; v8[6] = t1.z + e1.z; v8[7] = t1.w + e1.w;
  }
  split8v(v8, fh, fl);
  *(frag8*)&Ah[r * 72 + kf] = fh; *(frag8*)&Al[r * 72 + kf] = fl;
  {
    float4 a = *(const float4*)&h[own];
    float4 c4 = *(const float4*)&h[own + 4];
    v8[0] = a.x; v8[1] = a.y; v8[2] = a.z; v8[3] = a.w;
    v8[4] = c4.x; v8[5] = c4.y; v8[6] = c4.z; v8[7] = c4.w;
    split8v(v8, fh, fl);
    *(frag8*)&Ah[CH + r * 72 + kf] = fh; *(frag8*)&Al[CH + r * 72 + kf] = fl;
  }
  #pragma unroll
  for (int z2 = 0; z2 < 2; z2++) {
    int ck = (2 + 2 * z2) * CH + r * 72 + kf;
    if (ENC) {
      *(frag8*)&Ah[ck] = *(const frag8*)&SXH[(size_t)(t * 2 + z2) * TSZ + own];
      *(frag8*)&Al[ck] = *(const frag8*)&SXL[(size_t)(t * 2 + z2) * TSZ + own];
    } else {
      float rsz = rs[z2 * NN + m];
      float4 s0 = *(const float4*)&SE[(size_t)(z2 * NN + m) * ND + kf];
      float4 s1 = *(const float4*)&SE[(size_t)(z2 * NN + m) * ND + kf + 4];
      v8[0] = fmaf(rsz, t0.x, s0.x); v8[1] = fmaf(rsz, t0.y, s0.y);
      v8[2] = fmaf(rsz, t0.z, s0.z); v8[3] = fmaf(rsz, t0.w, s0.w);
      v8[4] = fmaf(rsz, t1.x, s1.x); v8[5] = fmaf(rsz, t1.y, s1.y);
      v8[6] = fmaf(rsz, t1.z, s1.z); v8[7] = fmaf(rsz, t1.w, s1.w);
      split8v(v8, fh, fl);
      *(frag8*)&Ah[ck] = fh; *(frag8*)&Al[ck] = fl;
    }
  }
  int c0 = scnt[0], c1 = scnt[1];
  if (tid < 64) {
    if (tid < c0) { sI[0][tid] = idx[m * CAP + tid]; sV[0][tid] = val[m * CAP + tid]; }
  } else if (tid < 128) {
    int j = tid - 64;
    if (j < c1) { sI[1][j] = idx[(NN + m) * CAP + j]; sV[1][j] = val[(NN + m) * CAP + j]; }
  }
  __syncthreads();
  // inline gather S_z @ h -> chunks 3,5
  {
    int z = tid >> 7, lid = tid & 127;
    int gr = lid >> 2, qd = (lid & 3) * 16;
    int nz = scnt[z];
    float acc[16];
    #pragma unroll
    for (int i = 0; i < 16; i++) acc[i] = 0.f;
    const float* basep = h + (size_t)g * 2048 + gr * 64 + qd;
    for (int j = 0; j < nz; j++) {
      float v = sV[z][j];
      const float* src = basep + (size_t)sI[z][j] * 4096;
      float4 x0 = *(const float4*)src;
      float4 x1 = *(const float4*)(src + 4);
      float4 x2 = *(const float4*)(src + 8);
      float4 x3 = *(const float4*)(src + 12);
      acc[0] = fmaf(v, x0.x, acc[0]); acc[1] = fmaf(v, x0.y, acc[1]);
      acc[2] = fmaf(v, x0.z, acc[2]); acc[3] = fmaf(v, x0.w, acc[3]);
      acc[4] = fmaf(v, x1.x, acc[4]); acc[5] = fmaf(v, x1.y, acc[5]);
      acc[6] = fmaf(v, x1.z, acc[6]); acc[7] = fmaf(v, x1.w, acc[7]);
      acc[8] = fmaf(v, x2.x, acc[8]); acc[9] = fmaf(v, x2.y, acc[9]);
      acc[10] = fmaf(v, x2.z, acc[10]); acc[11] = fmaf(v, x2.w, acc[11]);
      acc[12] = fmaf(v, x3.x, acc[12]); acc[13] = fmaf(v, x3.y, acc[13]);
      acc[14] = fmaf(v, x3.z, acc[14]); acc[15] = fmaf(v, x3.w, acc[15]);
    }
    frag8 h0, l0, h1, l1;
    split8v(acc, h0, l0); split8v(acc + 8, h1, l1);
    int dA = (3 + 2 * z) * CH + gr * 72 + qd;
    *(frag8*)&Ah[dA] = h0; *(frag8*)&Ah[dA + 8] = h1;
    *(frag8*)&Al[dA] = l0; *(frag8*)&Al[dA + 8] = l1;
  }
  __syncthreads();
  // K=384 MFMA GEMM, bf16x3
  int rbase = (w & 1) * 16;
  int cbase = (w >> 1) * 64;
  int mrow = lane & 15, rq = (lane >> 4) * 8;
  f32x4 acc4[4];
  #pragma unroll
  for (int i = 0; i < 4; i++) acc4[i] = (f32x4)0.f;
  for (int kt = 0; kt < 12; kt++) {
    int chunk = kt >> 1, kin = (kt & 1) * 32;
    #pragma unroll
    for (int i = tid; i < 512; i += 256) {
      int n = i >> 2, q = (i & 3) * 8;
      *(frag8*)&Bh[n * 40 + q] = *(const frag8*)&Wh[n * 384 + kt * 32 + q];
      *(frag8*)&Bl[n * 40 + q] = *(const frag8*)&Wl[n * 384 + kt * 32 + q];
    }
    __syncthreads();
    int abase = chunk * CH + (rbase + mrow) * 72 + kin + rq;
    frag8 fah = *(const frag8*)&Ah[abase];
    frag8 fal = *(const frag8*)&Al[abase];
    #pragma unroll
    for (int ct = 0; ct < 4; ct++) {
      int c = cbase + ct * 16 + mrow;
      frag8 bh = *(const frag8*)&Bh[c * 40 + rq];
      frag8 bl = *(const frag8*)&Bl[c * 40 + rq];
      acc4[ct] = __builtin_amdgcn_mfma_f32_16x16x32_bf16(fah, bh, acc4[ct], 0, 0, 0);
      acc4[ct] = __builtin_amdgcn_mfma_f32_16x16x32_bf16(fal, bh, acc4[ct], 0, 0, 0);
      acc4[ct] = __builtin_amdgcn_mfma_f32_16x16x32_bf16(fah, bl, acc4[ct], 0, 0, 0);
    }
    __syncthreads();
  }
  #pragma unroll
  for (int ct = 0; ct < 4; ct++)
    #pragma unroll
    for (int gg = 0; gg < 4; gg++) {
      int rloc = rbase + (lane >> 4) * 4 + gg;
      size_t row = (size_t)(m * 64 + g * 32 + rloc);
      int c = cbase + ct * 16 + mrow;
      float vv = acc4[ct][gg] + bias[c];
      float sg = 1.f / (1.f + __expf(-vv));
      if (c < ND) {
        float hval = bf2f(Ah[CH + rloc * 72 + c]) + bf2f(Al[CH + rloc * 72 + c]);
        rh[row * ND + c] = sg * hval;
      } else {
        ubuf[row * ND + (c - ND)] = sg;
      }
    }
}

// ---------- Fused candidate kernel: inline S@rh gather + MFMA + GRU (+head) ----------
// Chunks: 0=x 1=rh 2=S0x 3=S0rh 4=S1x 5=S1rh
template<int ENC>
__global__ void __launch_bounds__(256, 2)
k_FC(int t, const float* __restrict__ Xe, const u16* __restrict__ SXH,
     const u16* __restrict__ SXL, const float* __restrict__ te,
     const float* __restrict__ E_se, const float* __restrict__ SE,
     const float* __restrict__ rs, const float* __restrict__ rhb,
     const float* __restrict__ ubuf, float* __restrict__ hbuf,
     const int* __restrict__ cnt, const int* __restrict__ idx,
     const float* __restrict__ val, const u16* __restrict__ Wh,
     const u16* __restrict__ Wl, const float* __restrict__ bias,
     const float* __restrict__ Wo1, const float* __restrict__ bo1,
     const float* __restrict__ Wo2, const float* __restrict__ bo2,
     float* __restrict__ out, int qidx) {
  int m = blockIdx.x >> 1, g = blockIdx.x & 1;
  int tid = threadIdx.x;
  int lane = tid & 63, w = tid >> 6;
  __shared__ u16 Ah[6 * CH], Al[6 * CH];
  __shared__ u16 Bh[64 * 40], Bl[64 * 40];
  __shared__ float hnewS[ENC ? 1 : 32][ENC ? 1 : 68];
  __shared__ int sI[2][CAP];
  __shared__ float sV[2][CAP];
  __shared__ int scnt[2];
  if (tid < 2) scnt[tid] = cnt[tid * NN + m];
  __syncthreads();

  int r = tid >> 3, kf = (tid & 7) * 8;
  int b = g * 32 + r;
  size_t own = (size_t)(m * 64 + b) * ND + kf;
  frag8 fh, fl;
  float v8[8];
  float4 t0, t1;
  if (ENC) {
    float4 a = *(const float4*)&Xe[(size_t)t * TSZ + own];
    float4 c4 = *(const float4*)&Xe[(size_t)t * TSZ + own + 4];
    v8[0] = a.x; v8[1] = a.y; v8[2] = a.z; v8[3] = a.w;
    v8[4] = c4.x; v8[5] = c4.y; v8[6] = c4.z; v8[7] = c4.w;
  } else {
    t0 = *(const float4*)&te[(size_t)(b * NT + t) * ND + kf];
    t1 = *(const float4*)&te[(size_t)(b * NT + t) * ND + kf + 4];
    float4 e0 = *(const float4*)&E_se[m * ND + kf];
    float4 e1 = *(const float4*)&E_se[m * ND + kf + 4];
    v8[0] = t0.x + e0.x; v8[1] = t0.y + e0.y; v8[2] = t0.z + e0.z; v8[3] = t0.w + e0.w;
    v8[4] = t1.x + e1.x; v8[5] = t1.y + e1.y; v8[6] = t1.z + e1.z; v8[7] = t1.w + e1.w;
  }
  split8v(v8, fh, fl);
  *(frag8*)&Ah[r * 72 + kf] = fh; *(frag8*)&Al[r * 72 + kf] = fl;
  {
    float4 a = *(const float4*)&rhb[own];
    float4 c4 = *(const float4*)&rhb[own + 4];
    v8[0] = a.x; v8[1] = a.y; v8[2] = a.z; v8[3] = a.w;
    v8[4] = c4.x; v8[5] = c4.y; v8[6] = c4.z; v8[7] = c4.w;
    split8v(v8, fh, fl);
    *(frag8*)&Ah[CH + r * 72 + kf] = fh; *(frag8*)&Al[CH + r * 72 + kf] = fl;
  }
  #pragma unroll
  for (int z2 = 0; z2 < 2; z2++) {
    int ck = (2 + 2 * z2) * CH + r * 72 + kf;
    if (ENC) {
      *(frag8*)&Ah[ck] = *(const frag8*)&SXH[(size_t)(t * 2 + z2) * TSZ + own];
      *(frag8*)&Al[ck] = *(const frag8*)&SXL[(size_t)(t * 2 + z2) * TSZ + own];
    } else {
      float rsz = rs[z2 * NN + m];
      float4 s0 = *(const float4*)&SE[(size_t)(z2 * NN + m) * ND + kf];
      float4 s1 = *(const float4*)&SE[(size_t)(z2 * NN + m) * ND + kf + 4];
      v8[0] = fmaf(rsz, t0.x, s0.x); v8[1] = fmaf(rsz, t0.y, s0.y);
      v8[2] = fmaf(rsz, t0.z, s0.z); v8[3] = fmaf(rsz, t0.w, s0.w);
      v8[4] = fmaf(rsz, t1.x, s1.x); v8[5] = fmaf(rsz, t1.y, s1.y);
      v8[6] = fmaf(rsz, t1.z, s1.z); v8[7] = fmaf(rsz, t1.w, s1.w);
      split8v(v8, fh, fl);
      *(frag8*)&Ah[ck] = fh; *(frag8*)&Al[ck] = fl;
    }
  }
  int c0 = scnt[0], c1 = scnt[1];
  if (tid < 64) {
    if (tid < c0) { sI[0][tid] = idx[m * CAP + tid]; sV[0][tid] = val[m * CAP + tid]; }
  } else if (tid < 128) {
    int j = tid - 64;
    if (j < c1) { sI[1][j] = idx[(NN + m) * CAP + j]; sV[1][j] = val[(NN + m) * CAP + j]; }
  }
  __syncthreads();
  {
    int z = tid >> 7, lid = tid & 127;
    int gr = lid >> 2, qd = (lid & 3) * 16;
    int nz = scnt[z];
    float acc[16];
    #pragma unroll
    for (int i = 0; i < 16; i++) acc[i] = 0.f;
    const float* basep = rhb + (size_t)g * 2048 + gr * 64 + qd;
    for (int j = 0; j < nz; j++) {
      float v = sV[z][j];
      const float* src = basep + (size_t)sI[z][j] * 4096;
      float4 x0 = *(const float4*)src;
      float4 x1 = *(const float4*)(src + 4);
      float4 x2 = *(const float4*)(src + 8);
      float4 x3 = *(const float4*)(src + 12);
      acc[0] = fmaf(v, x0.x, acc[0]); acc[1] = fmaf(v, x0.y, acc[1]);
      acc[2] = fmaf(v, x0.z, acc[2]); acc[3] = fmaf(v, x0.w, acc[3]);
      acc[4] = fmaf(v, x1.x, acc[4]); acc[5] = fmaf(v, x1.y, acc[5]);
      acc[6] = fmaf(v, x1.z, acc[6]); acc[7] = fmaf(v, x1.w, acc[7]);
      acc[8] = fmaf(v, x2.x, acc[8]); acc[9] = fmaf(v, x2.y, acc[9]);
      acc[10] = fmaf(v, x2.z, acc[10]); acc[11] = fmaf(v, x2.w, acc[11]);
      acc[12] = fmaf(v, x3.x, acc[12]); acc[13] = fmaf(v, x3.y, acc[13]);
      acc[14] = fmaf(v, x3.z, acc[14]); acc[15] = fmaf(v, x3.w, acc[15]);
    }
    frag8 h0, l0, h1, l1;
    split8v(acc, h0, l0); split8v(acc + 8, h1, l1);
    int dA = (3 + 2 * z) * CH + gr * 72 + qd;
    *(frag8*)&Ah[dA] = h0; *(frag8*)&Ah[dA + 8] = h1;
    *(frag8*)&Al[dA] = l0; *(frag8*)&Al[dA + 8] = l1;
  }
  __syncthreads();
  int rbase = (w & 1) * 16;
  int cbase = (w >> 1) * 32;
  int mrow = lane & 15, rq = (lane >> 4) * 8;
  f32x4 acc4[2];
  acc4[0] = (f32x4)0.f; acc4[1] = (f32x4)0.f;
  for (int kt = 0; kt < 12; kt++) {
    int chunk = kt >> 1, kin = (kt & 1) * 32;
    {
      int n = tid >> 2, q = (tid & 3) * 8;
      *(frag8*)&Bh[n * 40 + q] = *(const frag8*)&Wh[n * 384 + kt * 32 + q];
      *(frag8*)&Bl[n * 40 + q] = *(const frag8*)&Wl[n * 384 + kt * 32 + q];
    }
    __syncthreads();
    int abase = chunk * CH + (rbase + mrow) * 72 + kin + rq;
    frag8 fah = *(const frag8*)&Ah[abase];
    frag8 fal = *(const frag8*)&Al[abase];
    #pragma unroll
    for (int ct = 0; ct < 2; ct++) {
      int c = cbase + ct * 16 + mrow;
      frag8 bh = *(const frag8*)&Bh[c * 40 + rq];
      frag8 bl = *(const frag8*)&Bl[c * 40 + rq];
      acc4[ct] = __builtin_amdgcn_mfma_f32_16x16x32_bf16(fah, bh, acc4[ct], 0, 0, 0);
      acc4[ct] = __builtin_amdgcn_mfma_f32_16x16x32_bf16(fal, bh, acc4[ct], 0, 0, 0);
      acc4[ct] = __builtin_amdgcn_mfma_f32_16x16x32_bf16(fah, bl, acc4[ct], 0, 0, 0);
    }
    __syncthreads();
  }
  #pragma unroll
  for (int ct = 0; ct < 2; ct++)
    #pragma unroll
    for (int gg = 0; gg < 4; gg++) {
      int rloc = rbase + (lane >> 4) * 4 + gg;
      size_t row = (size_t)(m * 64 + g * 32 + rloc);
      int c = cbase + ct * 16 + mrow;
      float vv = acc4[ct][gg] + bias[c];
      float cv = tanhf(vv);
      float uu = ubuf[row * ND + c];
      float ho = hbuf[row * ND + c];
      float hn = uu * ho + (1.f - uu) * cv;
      hbuf[row * ND + c] = hn;
      if (!ENC) hnewS[rloc][c] = hn;
    }
  if (!ENC) {
    __syncthreads();
    if (tid < 128) {
      int r2 = tid >> 2;
      int dg = (tid & 3) * 16;
      int node = blockIdx.x >> 1;
      int bb = (blockIdx.x & 1) * 32 + r2;
      float p = 0.f;
      #pragma unroll
      for (int i = 0; i < 16; i++) {
        int d = dg + i;
        float a = bo1[d];
        #pragma unroll 8
        for (int k = 0; k < ND; k++) a = fmaf(hnewS[r2][k], Wo1[k * ND + d], a);
        a = a > 0.f ? a : 0.f;
        p = fmaf(a, Wo2[d], p);
      }
      p += __shfl_down(p, 2);
      p += __shfl_down(p, 1);
      if ((tid & 3) == 0)
        out[((size_t)bb * NQ + qidx) * NN + node] = p + bo2[0];
    }
  }
}

extern "C" void kernel_launch(void* const* d_in, const int* in_sizes, int n_in,
                              void* d_out, int out_size, void* d_ws, size_t ws_size,
                              hipStream_t stream) {
  const float* X     = (const float*)d_in[0];
  const int*   TE    = (const int*)  d_in[1];
  const float* S0    = (const float*)d_in[2];
  const float* S1    = (const float*)d_in[3];
  const float* W_te1 = (const float*)d_in[4];
  const float* b_te1 = (const float*)d_in[5];
  const float* W_te2 = (const float*)d_in[6];
  const float* b_te2 = (const float*)d_in[7];
  const float* E_se  = (const float*)d_in[8];
  const float* W_in1 = (const float*)d_in[9];
  const float* b_in1 = (const float*)d_in[10];
  const float* W_in2 = (const float*)d_in[11];
  const float* b_in2 = (const float*)d_in[12];
  const float* enc_Wg = (const float*)d_in[13];
  const float* enc_bg = (const float*)d_in[14];
  const float* enc_Wc = (const float*)d_in[15];
  const float* enc_bc = (const float*)d_in[16];
  const float* dec_Wg = (const float*)d_in[17];
  const float* dec_bg = (const float*)d_in[18];
  const float* dec_Wc = (const float*)d_in[19];
  const float* dec_bc = (const float*)d_in[20];
  const float* W_out1 = (const float*)d_in[21];
  const float* b_out1 = (const float*)d_in[22];
  const float* W_out2 = (const float*)d_in[23];
  const float* b_out2 = (const float*)d_in[24];
  float* out = (float*)d_out;
  float* ws = (float*)d_ws;

  // workspace (floats); total ~209 MB < 256 MiB
  float* te   = ws;                         // 98304
  float* h    = te + 98304;                 // TSZ
  float* rh   = h + TSZ;                    // TSZ
  float* u    = rh + TSZ;                   // TSZ
  float* Xe   = u + TSZ;                    // 12*TSZ (encoder only)
  float* csrV = Xe + 12 * (size_t)TSZ;      // 2*NN*CAP
  int*   csrI = (int*)(csrV + 2 * NN * CAP);
  int*   csrC = csrI + 2 * NN * CAP;        // 650 pad 1024
  float* rs   = (float*)(csrC + 1024);      // 650 pad 1024
  float* SE   = rs + 1024;                  // 2*NN*64
  u16* wbuf = (u16*)(SE + 2 * NN * ND);
  u16* egWh = wbuf;                         // 128*384
  u16* egWl = egWh + 49152;
  u16* dgWh = egWl + 49152;
  u16* dgWl = dgWh + 49152;
  u16* ecWh = dgWl + 49152;                 // 64*384
  u16* ecWl = ecWh + 24576;
  u16* dcWh = ecWl + 24576;
  u16* dcWl = dcWh + 24576;
  u16* SXH = dcWl + 24576;                  // 12*2*TSZ
  u16* SXL = SXH + 24 * (size_t)TSZ;

  k_te<<<NB * NT, ND, 0, stream>>>(TE, W_te1, b_te1, W_te2, b_te2, te);
  k_csr<<<dim3(NN, 2), 64, 0, stream>>>(S0, S1, csrC, csrI, csrV, rs);
  k_convW<<<384, 128, 0, stream>>>(enc_Wg, egWh, egWl, 128);
  k_convW<<<384, 128, 0, stream>>>(dec_Wg, dgWh, dgWl, 128);
  k_convW<<<384,  64, 0, stream>>>(enc_Wc, ecWh, ecWl, 64);
  k_convW<<<384,  64, 0, stream>>>(dec_Wc, dcWh, dcWl, 64);
  k_zero<<<(TSZ + 255) / 256, 256, 0, stream>>>(h, TSZ);
  k_xe<<<dim3(NR / 16, NP), 256, 0, stream>>>(X, te, E_se, W_in1, b_in1, W_in2, b_in2, Xe);
  k_se<<<dim3(NN, 2), 64, 0, stream>>>(E_se, csrC, csrI, csrV, SE);
  k_sxe<<<dim3(8, NN, NP), 256, 0, stream>>>(Xe, csrC, csrI, csrV, SXH, SXL);

  for (int t = 0; t < NT; t++) {
    if (t < NP) {
      k_FG<1><<<NN * 2, 256, 0, stream>>>(t, Xe, SXH, SXL, te, E_se, SE, rs, h,
                                          csrC, csrI, csrV, egWh, egWl, enc_bg, rh, u);
      k_FC<1><<<NN * 2, 256, 0, stream>>>(t, Xe, SXH, SXL, te, E_se, SE, rs, rh, u, h,
                                          csrC, csrI, csrV, ecWh, ecWl, enc_bc,
                                          W_out1, b_out1, W_out2, b_out2, out, 0);
    } else {
      k_FG<0><<<NN * 2, 256, 0, stream>>>(t, Xe, SXH, SXL, te, E_se, SE, rs, h,
                                          csrC, csrI, csrV, dgWh, dgWl, dec_bg, rh, u);
      k_FC<0><<<NN * 2, 256, 0, stream>>>(t, Xe, SXH, SXL, te, E_se, SE, rs, rh, u, h,
                                          csrC, csrI, csrV, dcWh, dcWl, dec_bc,
                                          W_out1, b_out1, W_out2, b_out2, out, t - NP);
    }
  }
}